// Round 2
// baseline (138.660 us; speedup 1.0000x reference)
//
#include <hip/hip_runtime.h>
#include <hip/hip_bf16.h>

#define CAP 192   // per-node bin capacity; Poisson(64) max over 10000 nodes ~110

typedef __bf16 bf16_8 __attribute__((ext_vector_type(8)));
typedef float f32_4 __attribute__((ext_vector_type(4)));

// ---------------------------------------------------------------------------
// k_init: zero counters + overflow buffer, convert x and W to bf16.
// ---------------------------------------------------------------------------
__global__ void k_init(const float* __restrict__ x, const float* __restrict__ W,
                       __hip_bfloat16* __restrict__ xb, __hip_bfloat16* __restrict__ Wb,
                       float* __restrict__ ovf, int* __restrict__ count,
                       int nx, int nW, int N) {
  int i = blockIdx.x * blockDim.x + threadIdx.x;
  if (i < nx) {
    xb[i] = __float2bfloat16(x[i]);
    ovf[i] = 0.f;
  }
  if (i < nW) Wb[i] = __float2bfloat16(W[i]);
  if (i < N) count[i] = 0;
}

// ---------------------------------------------------------------------------
// k_bin: single-pass degree count + binning. Overflow (never in practice)
// falls back to fp32 atomicAdd into ovf for guaranteed correctness.
// ---------------------------------------------------------------------------
__global__ void k_bin(const int* __restrict__ ei, int E, int* __restrict__ count,
                      int* __restrict__ bins, float* __restrict__ ovf,
                      const float* __restrict__ x) {
  int e = blockIdx.x * blockDim.x + threadIdx.x;
  if (e >= E) return;
  int s = ei[e];
  int d = ei[E + e];
  int pos = atomicAdd(&count[d], 1);
  if (pos < CAP) {
    bins[d * CAP + pos] = s;
  } else {
    const float* xs = x + (size_t)s * 128;
    float* o = ovf + (size_t)d * 128;
    for (int k = 0; k < 128; ++k) atomicAdd(&o[k], xs[k]);
  }
}

// ---------------------------------------------------------------------------
// k_agg: one wave per node. Lane holds dims (2*lane, 2*lane+1) as bf16x2
// gathers (256 B per row per wave). h = agg/deg + x, written as bf16 for GEMM.
// ---------------------------------------------------------------------------
__global__ void k_agg(const int* __restrict__ count, const int* __restrict__ bins,
                      const __hip_bfloat162* __restrict__ xb2,
                      const float2* __restrict__ ovf2, const float2* __restrict__ x2,
                      __hip_bfloat162* __restrict__ hb2, int N) {
  int n = blockIdx.x * 4 + (threadIdx.x >> 6);
  if (n >= N) return;
  int lane = threadIdx.x & 63;
  int cnt = count[n];
  int m = cnt < CAP ? cnt : CAP;
  const int* bn = bins + n * CAP;
  float ax = 0.f, ay = 0.f;
  int e = 0;
  for (; e + 4 <= m; e += 4) {
    int s0 = bn[e], s1 = bn[e + 1], s2 = bn[e + 2], s3 = bn[e + 3];
    float2 v0 = __bfloat1622float2(xb2[s0 * 64 + lane]);
    float2 v1 = __bfloat1622float2(xb2[s1 * 64 + lane]);
    float2 v2 = __bfloat1622float2(xb2[s2 * 64 + lane]);
    float2 v3 = __bfloat1622float2(xb2[s3 * 64 + lane]);
    ax += v0.x + v1.x + v2.x + v3.x;
    ay += v0.y + v1.y + v2.y + v3.y;
  }
  for (; e < m; ++e) {
    float2 v = __bfloat1622float2(xb2[bn[e] * 64 + lane]);
    ax += v.x;
    ay += v.y;
  }
  if (cnt > CAP) {  // overflow fallback path (wave-uniform branch, ~never)
    float2 o = ovf2[n * 64 + lane];
    ax += o.x;
    ay += o.y;
  }
  float deg = (float)(cnt > 0 ? cnt : 1);
  float2 xr = x2[n * 64 + lane];
  float hx = ax / deg + xr.x;
  float hy = ay / deg + xr.y;
  hb2[n * 64 + lane] = __halves2bfloat162(__float2bfloat16(hx), __float2bfloat16(hy));
}

// ---------------------------------------------------------------------------
// k_gemm: out = relu(h @ W^T + b), MFMA bf16 16x16x32, fp32 accumulate.
// einsum('nd,od->no'): B-fragment B[k][n] = W[n][k] -> read W rows directly.
// A frag:  A[m=lane&15][k=quad*8+j]      (16B contiguous load)
// B frag:  B[k=quad*8+j][n=lane&15]      (16B contiguous load from W row)
// C/D:     col=lane&15, row=quad*4+reg   (verified layout, m89)
// Block = 256 thr (4 waves) = one 16-row tile; each wave does 2 col tiles.
// ---------------------------------------------------------------------------
__global__ void k_gemm(const __hip_bfloat16* __restrict__ hb,
                       const __hip_bfloat16* __restrict__ Wb,
                       const float* __restrict__ bias,
                       float* __restrict__ out, int N) {
  int rowbase = blockIdx.x * 16;
  int wid = threadIdx.x >> 6;
  int lane = threadIdx.x & 63;
  int m16 = lane & 15;
  int quad = lane >> 4;

  // A fragments for this row tile (reused across both col tiles)
  bf16_8 a[4];
  const __hip_bfloat16* arow = hb + (size_t)(rowbase + m16) * 128 + quad * 8;
#pragma unroll
  for (int kk = 0; kk < 4; ++kk) a[kk] = *(const bf16_8*)(arow + kk * 32);

#pragma unroll
  for (int ct = 0; ct < 2; ++ct) {
    int colbase = wid * 32 + ct * 16;
    const __hip_bfloat16* brow = Wb + (size_t)(colbase + m16) * 128 + quad * 8;
    f32_4 c = {0.f, 0.f, 0.f, 0.f};
#pragma unroll
    for (int kk = 0; kk < 4; ++kk) {
      bf16_8 bb = *(const bf16_8*)(brow + kk * 32);
      c = __builtin_amdgcn_mfma_f32_16x16x32_bf16(a[kk], bb, c, 0, 0, 0);
    }
    float bv = bias[colbase + m16];
#pragma unroll
    for (int r = 0; r < 4; ++r) {
      int row = rowbase + quad * 4 + r;
      float v = c[r] + bv;
      out[(size_t)row * 128 + colbase + m16] = v > 0.f ? v : 0.f;
    }
  }
}

// ---------------------------------------------------------------------------
extern "C" void kernel_launch(void* const* d_in, const int* in_sizes, int n_in,
                              void* d_out, int out_size, void* d_ws, size_t ws_size,
                              hipStream_t stream) {
  const float* x = (const float*)d_in[0];
  const int* ei = (const int*)d_in[1];
  const float* W = (const float*)d_in[2];
  const float* b = (const float*)d_in[3];
  float* out = (float*)d_out;

  const int N = in_sizes[0] / 128;  // 10000
  const int E = in_sizes[1] / 2;    // 640000
  const int nx = N * 128;           // 1,280,000
  const int nW = 128 * 128;         // 16,384

  // workspace carve-up (256B aligned)
  char* ws = (char*)d_ws;
  size_t off = 0;
  auto carve = [&](size_t bytes) {
    void* p = ws + off;
    off = (off + bytes + 255) & ~(size_t)255;
    return p;
  };
  int* bins = (int*)carve((size_t)N * CAP * sizeof(int));             // 7.68 MB
  int* count = (int*)carve((size_t)N * sizeof(int));                  // 40 KB
  float* ovf = (float*)carve((size_t)nx * sizeof(float));             // 5.12 MB
  __hip_bfloat16* xb = (__hip_bfloat16*)carve((size_t)nx * 2);        // 2.56 MB
  __hip_bfloat16* Wb = (__hip_bfloat16*)carve((size_t)nW * 2);        // 32 KB
  __hip_bfloat16* hb = (__hip_bfloat16*)carve((size_t)nx * 2);        // 2.56 MB

  // 1) init: zero count/ovf, convert x,W to bf16
  k_init<<<(nx + 255) / 256, 256, 0, stream>>>(x, W, xb, Wb, ovf, count, nx, nW, N);
  // 2) bin edges by destination
  k_bin<<<(E + 255) / 256, 256, 0, stream>>>(ei, E, count, bins, ovf, x);
  // 3) aggregate (one wave per node) -> h (bf16)
  k_agg<<<(N + 3) / 4, 256, 0, stream>>>(count, bins, (const __hip_bfloat162*)xb,
                                         (const float2*)ovf, (const float2*)x,
                                         (__hip_bfloat162*)hb, N);
  // 4) GEMM + bias + relu (MFMA bf16)
  k_gemm<<<(N + 15) / 16, 256, 0, stream>>>(hb, Wb, b, out, N);
}

// Round 3
// 134.781 us; speedup vs baseline: 1.0288x; 1.0288x over previous
//
#include <hip/hip_runtime.h>
#include <hip/hip_bf16.h>

#define CAP 192   // per-node bin capacity; max degree for 640K edges over 10K nodes ~110

typedef __bf16 bf16_8 __attribute__((ext_vector_type(8)));
typedef float f32_4 __attribute__((ext_vector_type(4)));

// ---------------------------------------------------------------------------
// k_init: zero count + overflow accumulator, convert x and W to bf16 (vectorized).
// ---------------------------------------------------------------------------
__global__ void k_init(const float2* __restrict__ x2, const float2* __restrict__ W2,
                       __hip_bfloat162* __restrict__ xb2, __hip_bfloat162* __restrict__ Wb2,
                       float2* __restrict__ ovf2, int* __restrict__ count,
                       int nx2, int nW2, int N) {
  int i = blockIdx.x * blockDim.x + threadIdx.x;
  if (i < nx2) {
    float2 v = x2[i];
    xb2[i] = __halves2bfloat162(__float2bfloat16(v.x), __float2bfloat16(v.y));
    ovf2[i] = make_float2(0.f, 0.f);
  }
  if (i < nW2) {
    float2 w = W2[i];
    Wb2[i] = __halves2bfloat162(__float2bfloat16(w.x), __float2bfloat16(w.y));
  }
  if (i < N) count[i] = 0;
}

// ---------------------------------------------------------------------------
// k_zgemm: z = x @ W^T (bf16 MFMA 16x16x32, fp32 acc, bf16 store).
// einsum('nd,od->no'): B[k=d][n=o] = W[o][d] -> read W rows directly.
// A frag: A[m=lane&15][k=quad*8+j]; C/D: col=lane&15, row=quad*4+reg.
// ---------------------------------------------------------------------------
__global__ void k_zgemm(const __hip_bfloat16* __restrict__ xb,
                        const __hip_bfloat16* __restrict__ Wb,
                        __hip_bfloat16* __restrict__ zb, int N) {
  int rowbase = blockIdx.x * 16;
  int wid = threadIdx.x >> 6;
  int lane = threadIdx.x & 63;
  int m16 = lane & 15;
  int quad = lane >> 4;

  bf16_8 a[4];
  const __hip_bfloat16* arow = xb + (size_t)(rowbase + m16) * 128 + quad * 8;
#pragma unroll
  for (int kk = 0; kk < 4; ++kk) a[kk] = *(const bf16_8*)(arow + kk * 32);

#pragma unroll
  for (int ct = 0; ct < 2; ++ct) {
    int colbase = wid * 32 + ct * 16;
    const __hip_bfloat16* brow = Wb + (size_t)(colbase + m16) * 128 + quad * 8;
    f32_4 c = {0.f, 0.f, 0.f, 0.f};
#pragma unroll
    for (int kk = 0; kk < 4; ++kk) {
      bf16_8 bb = *(const bf16_8*)(brow + kk * 32);
      c = __builtin_amdgcn_mfma_f32_16x16x32_bf16(a[kk], bb, c, 0, 0, 0);
    }
#pragma unroll
    for (int r = 0; r < 4; ++r) {
      int row = rowbase + quad * 4 + r;
      zb[(size_t)row * 128 + colbase + m16] = __float2bfloat16(c[r]);
    }
  }
}

// ---------------------------------------------------------------------------
// k_bin: single-pass degree count + binning by destination. Overflow (never in
// practice) atomically accumulates z rows into ovf for guaranteed correctness.
// ---------------------------------------------------------------------------
__global__ void k_bin(const int* __restrict__ ei, int E, int* __restrict__ count,
                      int* __restrict__ bins, float* __restrict__ ovf,
                      const __hip_bfloat16* __restrict__ zb) {
  int e = blockIdx.x * blockDim.x + threadIdx.x;
  if (e >= E) return;
  int s = ei[e];
  int d = ei[E + e];
  int pos = atomicAdd(&count[d], 1);
  if (pos < CAP) {
    bins[d * CAP + pos] = s;
  } else {
    const __hip_bfloat16* zs = zb + (size_t)s * 128;
    float* o = ovf + (size_t)d * 128;
    for (int k = 0; k < 128; ++k) atomicAdd(&o[k], __bfloat162float(zs[k]));
  }
}

// ---------------------------------------------------------------------------
// k_agg: one wave per node; quarter-wave per z-row (16 lanes x 16B dwordx4 =
// 256B row), so each loop trip gathers up to 16 edges with 4 loads in flight.
// Cross-group reduce via shfl_xor(16,32), then fused /deg + z[n] + b + relu.
// ---------------------------------------------------------------------------
__global__ void k_agg(const int* __restrict__ count, const int* __restrict__ bins,
                      const __hip_bfloat16* __restrict__ zb,
                      const float* __restrict__ ovf,
                      const float* __restrict__ bias,
                      float* __restrict__ out, int N) {
  int n = blockIdx.x * 4 + (threadIdx.x >> 6);
  if (n >= N) return;
  int lane = threadIdx.x & 63;
  int g = lane >> 4;     // row-group 0..3
  int sub = lane & 15;   // 16B chunk within the 256B row
  int cnt = count[n];
  int m = cnt < CAP ? cnt : CAP;
  const int* bn = bins + n * CAP;

  float acc[8] = {0.f, 0.f, 0.f, 0.f, 0.f, 0.f, 0.f, 0.f};
  for (int e = 0; e < m; e += 16) {
#pragma unroll
    for (int u = 0; u < 4; ++u) {
      int idx = e + u * 4 + g;
      if (idx < m) {
        int s = bn[idx];
        bf16_8 v = *(const bf16_8*)(zb + (size_t)s * 128 + sub * 8);
#pragma unroll
        for (int k = 0; k < 8; ++k) acc[k] += (float)v[k];
      }
    }
  }
  // reduce the 4 row-groups: every lane ends with the full segment sum
#pragma unroll
  for (int k = 0; k < 8; ++k) {
    acc[k] += __shfl_xor(acc[k], 16);
    acc[k] += __shfl_xor(acc[k], 32);
  }

  if (g == 0) {  // lanes 0..15 write the 512B output row
    float inv = 1.f / (float)(cnt > 0 ? cnt : 1);
    bf16_8 zn = *(const bf16_8*)(zb + (size_t)n * 128 + sub * 8);
    float r[8];
#pragma unroll
    for (int k = 0; k < 8; ++k) {
      float a = acc[k];
      if (cnt > CAP) a += ovf[(size_t)n * 128 + sub * 8 + k];
      float v = a * inv + (float)zn[k] + bias[sub * 8 + k];
      r[k] = v > 0.f ? v : 0.f;
    }
    float* o = out + (size_t)n * 128 + sub * 8;
    *(float4*)(o)     = make_float4(r[0], r[1], r[2], r[3]);
    *(float4*)(o + 4) = make_float4(r[4], r[5], r[6], r[7]);
  }
}

// ---------------------------------------------------------------------------
extern "C" void kernel_launch(void* const* d_in, const int* in_sizes, int n_in,
                              void* d_out, int out_size, void* d_ws, size_t ws_size,
                              hipStream_t stream) {
  const float* x = (const float*)d_in[0];
  const int* ei = (const int*)d_in[1];
  const float* W = (const float*)d_in[2];
  const float* b = (const float*)d_in[3];
  float* out = (float*)d_out;

  const int N = in_sizes[0] / 128;  // 10000
  const int E = in_sizes[1] / 2;    // 640000
  const int nx = N * 128;           // 1,280,000
  const int nW = 128 * 128;         // 16,384

  char* ws = (char*)d_ws;
  size_t off = 0;
  auto carve = [&](size_t bytes) {
    void* p = ws + off;
    off = (off + bytes + 255) & ~(size_t)255;
    return p;
  };
  int* bins = (int*)carve((size_t)N * CAP * sizeof(int));             // 7.68 MB
  int* count = (int*)carve((size_t)N * sizeof(int));                  // 40 KB
  float* ovf = (float*)carve((size_t)nx * sizeof(float));             // 5.12 MB
  __hip_bfloat16* xb = (__hip_bfloat16*)carve((size_t)nx * 2);        // 2.56 MB
  __hip_bfloat16* Wb = (__hip_bfloat16*)carve((size_t)nW * 2);        // 32 KB
  __hip_bfloat16* zb = (__hip_bfloat16*)carve((size_t)nx * 2);        // 2.56 MB

  // 1) init: zero count/ovf, convert x,W to bf16 (float2-vectorized)
  k_init<<<(nx / 2 + 255) / 256, 256, 0, stream>>>(
      (const float2*)x, (const float2*)W, (__hip_bfloat162*)xb,
      (__hip_bfloat162*)Wb, (float2*)ovf, count, nx / 2, nW / 2, N);
  // 2) z = x @ W^T (bf16)
  k_zgemm<<<(N + 15) / 16, 256, 0, stream>>>(xb, Wb, zb, N);
  // 3) bin edges by destination
  k_bin<<<(E + 255) / 256, 256, 0, stream>>>(ei, E, count, bins, ovf, zb);
  // 4) gather z rows, reduce, fused /deg + z[n] + bias + relu -> out
  k_agg<<<(N + 3) / 4, 256, 0, stream>>>(count, bins, zb, ovf, b, out, N);
}

// Round 4
// 130.029 us; speedup vs baseline: 1.0664x; 1.0365x over previous
//
#include <hip/hip_runtime.h>
#include <hip/hip_bf16.h>

#define NREP 4    // counter/bin replicas: contention 64 -> 16 per address
#define CAPR 64   // per-replica capacity; per-replica degree ~ Poisson(16), P(>=64) ~ 1e-18

typedef __bf16 bf16_8 __attribute__((ext_vector_type(8)));
typedef float f32_4 __attribute__((ext_vector_type(4)));
typedef float f32_8 __attribute__((ext_vector_type(8)));

// ---------------------------------------------------------------------------
// k_init: zero replica counters (each padded to its own 64B line) + ovf count.
// ---------------------------------------------------------------------------
__global__ void k_init(int4* __restrict__ cnt4, int* __restrict__ ovf_cnt, int n4) {
  int i = blockIdx.x * 256 + threadIdx.x;
  if (i < n4) cnt4[i] = make_int4(0, 0, 0, 0);
  if (i == 0) *ovf_cnt = 0;
}

// ---------------------------------------------------------------------------
// k_fused: blockIdx-split roles (wave-uniform):
//  blocks [0,625):    z = x @ W^T  (bf16 MFMA, fp32->bf16 convert inline)
//  blocks [625,1250): edge binning, 4 edges/thread (4 atomics in flight),
//                     replica r=u so each thread's atomics hit 4 distinct lines.
// The latency-bound bin role hides the tiny GEMM underneath it.
// ---------------------------------------------------------------------------
__global__ void k_fused(const float* __restrict__ x, const float* __restrict__ W,
                        const int* __restrict__ ei, int E, int N,
                        __hip_bfloat16* __restrict__ zb, int* __restrict__ cnt,
                        unsigned short* __restrict__ bins,
                        int* __restrict__ ovf_cnt, int2* __restrict__ ovf_list) {
  if (blockIdx.x < 625) {
    // ---- zgemm role: einsum('nd,od->no') => B[k][n] = W[n][k], read W rows.
    // A frag: A[m=lane&15][k=quad*8+j]; C/D: col=lane&15, row=quad*4+reg (m89).
    int rowbase = blockIdx.x * 16;
    int wid = threadIdx.x >> 6;
    int lane = threadIdx.x & 63;
    int m16 = lane & 15;
    int quad = lane >> 4;

    union { bf16_8 v; __hip_bfloat16 h[8]; } ac[4];
    const float* arow = x + (size_t)(rowbase + m16) * 128 + quad * 8;
#pragma unroll
    for (int kk = 0; kk < 4; ++kk) {
      f32_8 af = *(const f32_8*)(arow + kk * 32);
#pragma unroll
      for (int j = 0; j < 8; ++j) ac[kk].h[j] = __float2bfloat16(af[j]);
    }

#pragma unroll
    for (int ct = 0; ct < 2; ++ct) {
      int colbase = wid * 32 + ct * 16;
      const float* brow = W + (size_t)(colbase + m16) * 128 + quad * 8;
      f32_4 c = {0.f, 0.f, 0.f, 0.f};
#pragma unroll
      for (int kk = 0; kk < 4; ++kk) {
        f32_8 bf = *(const f32_8*)(brow + kk * 32);
        union { bf16_8 v; __hip_bfloat16 h[8]; } bc;
#pragma unroll
        for (int j = 0; j < 8; ++j) bc.h[j] = __float2bfloat16(bf[j]);
        c = __builtin_amdgcn_mfma_f32_16x16x32_bf16(ac[kk].v, bc.v, c, 0, 0, 0);
      }
#pragma unroll
      for (int r = 0; r < 4; ++r) {
        int row = rowbase + quad * 4 + r;
        zb[(size_t)row * 128 + colbase + m16] = __float2bfloat16(c[r]);
      }
    }
  } else {
    // ---- bin role: 4 edges/thread, replica = in-thread slot u.
    int t = (blockIdx.x - 625) * 256 + threadIdx.x;  // 0..159999
    int4 s4 = ((const int4*)ei)[t];
    int4 d4 = ((const int4*)(ei + E))[t];
    int ss[4] = {s4.x, s4.y, s4.z, s4.w};
    int dd[4] = {d4.x, d4.y, d4.z, d4.w};
    int pos[4];
#pragma unroll
    for (int u = 0; u < 4; ++u)
      pos[u] = atomicAdd(&cnt[(u * N + dd[u]) << 4], 1);  // 4 independent, in flight
#pragma unroll
    for (int u = 0; u < 4; ++u) {
      if (pos[u] < CAPR) {
        bins[(dd[u] * NREP + u) * CAPR + pos[u]] = (unsigned short)ss[u];
      } else {  // statistically never; guaranteed-correct fallback
        int w = atomicAdd(ovf_cnt, 1);
        ovf_list[w] = make_int2(ss[u], dd[u]);
      }
    }
  }
}

// ---------------------------------------------------------------------------
// k_agg: one wave per node. 16-lane group g handles replica segment g;
// lane sub = 16B chunk of the 256B z-row. Unroll 8 => 8 gathers in flight.
// Cross-group shfl_xor(16,32) sums the 4 segments; fused /deg + z[n] + b + relu.
// ---------------------------------------------------------------------------
__global__ void k_agg(const int* __restrict__ cnt, const unsigned short* __restrict__ bins,
                      const __hip_bfloat16* __restrict__ zb,
                      const float* __restrict__ bias,
                      const int* __restrict__ ovf_cnt, const int2* __restrict__ ovf_list,
                      float* __restrict__ out, int N) {
  int n = blockIdx.x * 4 + (threadIdx.x >> 6);
  if (n >= N) return;
  int lane = threadIdx.x & 63;
  int g = lane >> 4;     // replica segment
  int sub = lane & 15;   // 16B chunk within row

  int craw = cnt[(g * N + n) << 4];
  int m = craw < CAPR ? craw : CAPR;
  const unsigned short* bs = bins + (n * NREP + g) * CAPR;

  float acc[8] = {0.f, 0.f, 0.f, 0.f, 0.f, 0.f, 0.f, 0.f};
  for (int e = 0; e < m; e += 8) {
#pragma unroll
    for (int u = 0; u < 8; ++u) {
      int idx = e + u;
      if (idx < m) {
        int s = bs[idx];
        bf16_8 v = *(const bf16_8*)(zb + (size_t)s * 128 + sub * 8);
#pragma unroll
        for (int k = 0; k < 8; ++k) acc[k] += (float)v[k];
      }
    }
  }

  int oc = *ovf_cnt;  // ~always 0
  for (int i = g; i < oc; i += 4) {
    int2 e2 = ovf_list[i];
    if (e2.y == n) {
      bf16_8 v = *(const bf16_8*)(zb + (size_t)e2.x * 128 + sub * 8);
#pragma unroll
      for (int k = 0; k < 8; ++k) acc[k] += (float)v[k];
    }
  }

  // true degree = sum of raw replica counts (includes overflow edges)
  int tot = craw;
  tot += __shfl_xor(tot, 16);
  tot += __shfl_xor(tot, 32);
#pragma unroll
  for (int k = 0; k < 8; ++k) {
    acc[k] += __shfl_xor(acc[k], 16);
    acc[k] += __shfl_xor(acc[k], 32);
  }

  if (g == 0) {  // lanes 0..15 write the 512B output row
    float inv = 1.f / (float)(tot > 0 ? tot : 1);
    bf16_8 zn = *(const bf16_8*)(zb + (size_t)n * 128 + sub * 8);
    float r[8];
#pragma unroll
    for (int k = 0; k < 8; ++k) {
      float v = acc[k] * inv + (float)zn[k] + bias[sub * 8 + k];
      r[k] = v > 0.f ? v : 0.f;
    }
    float* o = out + (size_t)n * 128 + sub * 8;
    *(float4*)(o)     = make_float4(r[0], r[1], r[2], r[3]);
    *(float4*)(o + 4) = make_float4(r[4], r[5], r[6], r[7]);
  }
}

// ---------------------------------------------------------------------------
extern "C" void kernel_launch(void* const* d_in, const int* in_sizes, int n_in,
                              void* d_out, int out_size, void* d_ws, size_t ws_size,
                              hipStream_t stream) {
  const float* x = (const float*)d_in[0];
  const int* ei = (const int*)d_in[1];
  const float* W = (const float*)d_in[2];
  const float* b = (const float*)d_in[3];
  float* out = (float*)d_out;

  const int N = in_sizes[0] / 128;  // 10000
  const int E = in_sizes[1] / 2;    // 640000

  char* ws = (char*)d_ws;
  size_t off = 0;
  auto carve = [&](size_t bytes) {
    void* p = ws + off;
    off = (off + bytes + 255) & ~(size_t)255;
    return p;
  };
  int* cnt = (int*)carve((size_t)N * NREP * 16 * sizeof(int));          // 2.56 MB (line-padded)
  unsigned short* bins = (unsigned short*)carve((size_t)N * NREP * CAPR * 2);  // 5.12 MB
  int* ovf_cnt = (int*)carve(sizeof(int));
  int2* ovf_list = (int2*)carve((size_t)E * sizeof(int2));              // 5.12 MB (bulletproof)
  __hip_bfloat16* zb = (__hip_bfloat16*)carve((size_t)N * 128 * 2);     // 2.56 MB

  const int ncnt4 = N * NREP * 16 / 4;  // 160000 int4 stores

  // 1) zero counters + overflow count
  k_init<<<(ncnt4 + 255) / 256, 256, 0, stream>>>((int4*)cnt, ovf_cnt, ncnt4);
  // 2) fused: z = x@W^T (blocks 0..624)  ||  edge binning (blocks 625..1249)
  k_fused<<<1250, 256, 0, stream>>>(x, W, ei, E, N, zb, cnt, bins, ovf_cnt, ovf_list);
  // 3) gather + segment-sum + /deg + z[n] + bias + relu
  k_agg<<<(N + 3) / 4, 256, 0, stream>>>(cnt, bins, zb, b, ovf_cnt, ovf_list, out, N);
}

// Round 5
// 111.128 us; speedup vs baseline: 1.2477x; 1.1701x over previous
//
#include <hip/hip_runtime.h>
#include <hip/hip_bf16.h>

// Problem constants (fixed by the reference): N=10000 nodes, 128 dims, E=640000.
#define NB    128      // sort blocks; each owns E/NB = 5000 edges
#define EPB   5000     // edges per block
#define NPAD  10240    // 256 threads * 40 nodes each (>= N)
#define NPT   40       // nodes per thread in the scan
#define LCAP  1024     // per-wave src-list capacity (max degree; Poisson(64) => impossible to exceed)

typedef __bf16 bf16_8 __attribute__((ext_vector_type(8)));
typedef float f32_4 __attribute__((ext_vector_type(4)));
typedef float f32_8 __attribute__((ext_vector_type(8)));

// ---------------------------------------------------------------------------
// k_zgemm: z = x @ W^T (bf16 MFMA 16x16x32, inline fp32->bf16 converts).
// einsum('nd,od->no') => B[k][n] = W[n][k]: read W rows directly.
// A frag: A[m=lane&15][k=quad*8+j]; C/D: col=lane&15, row=quad*4+reg (m89).
// ---------------------------------------------------------------------------
__global__ void k_zgemm(const float* __restrict__ x, const float* __restrict__ W,
                        __hip_bfloat16* __restrict__ zb) {
  int rowbase = blockIdx.x * 16;
  int wid = threadIdx.x >> 6;
  int lane = threadIdx.x & 63;
  int m16 = lane & 15;
  int quad = lane >> 4;

  union { bf16_8 v; __hip_bfloat16 h[8]; } ac[4];
  const float* arow = x + (size_t)(rowbase + m16) * 128 + quad * 8;
#pragma unroll
  for (int kk = 0; kk < 4; ++kk) {
    f32_8 af = *(const f32_8*)(arow + kk * 32);
#pragma unroll
    for (int j = 0; j < 8; ++j) ac[kk].h[j] = __float2bfloat16(af[j]);
  }

#pragma unroll
  for (int ct = 0; ct < 2; ++ct) {
    int colbase = wid * 32 + ct * 16;
    const float* brow = W + (size_t)(colbase + m16) * 128 + quad * 8;
    f32_4 c = {0.f, 0.f, 0.f, 0.f};
#pragma unroll
    for (int kk = 0; kk < 4; ++kk) {
      f32_8 bf = *(const f32_8*)(brow + kk * 32);
      union { bf16_8 v; __hip_bfloat16 h[8]; } bc;
#pragma unroll
      for (int j = 0; j < 8; ++j) bc.h[j] = __float2bfloat16(bf[j]);
      c = __builtin_amdgcn_mfma_f32_16x16x32_bf16(ac[kk].v, bc.v, c, 0, 0, 0);
    }
#pragma unroll
    for (int r = 0; r < 4; ++r) {
      int row = rowbase + quad * 4 + r;
      zb[(size_t)row * 128 + colbase + m16] = __float2bfloat16(c[r]);
    }
  }
}

// ---------------------------------------------------------------------------
// k_sortbin: per-block counting sort of this block's 5000 edges by dst.
// ZERO global atomics. Outputs:
//   bins[b][0..4999]  (ushort src, grouped by dst, coalesced write)
//   combo[n][b] = (count<<16) | excl_offset   (uint; k_agg reads row [n][*])
// ---------------------------------------------------------------------------
__global__ void k_sortbin(const int* __restrict__ ei, int E,
                          unsigned short* __restrict__ bins,
                          unsigned int* __restrict__ combo) {
  __shared__ int cnt[NPAD];                 // 40.96 KB: histogram -> cursors
  __shared__ unsigned short sorted[EPB];    // 10 KB
  __shared__ int wsum[4];

  const int t = threadIdx.x;
  const int b = blockIdx.x;
  const int4* src4 = (const int4*)(ei) + b * (EPB / 4);
  const int4* dst4 = (const int4*)(ei + E) + b * (EPB / 4);

  for (int i = t; i < NPAD; i += 256) cnt[i] = 0;
  __syncthreads();

  // Pass A: histogram (LDS atomics, no return needed)
  for (int i = t; i < EPB / 4; i += 256) {
    int4 d4 = dst4[i];
    atomicAdd(&cnt[d4.x], 1);
    atomicAdd(&cnt[d4.y], 1);
    atomicAdd(&cnt[d4.z], 1);
    atomicAdd(&cnt[d4.w], 1);
  }
  __syncthreads();

  // Pass B: block-wide exclusive scan of cnt[0..NPAD), emit combo.
  int raw[NPT];
  const int lo = t * NPT;
  int sum = 0;
#pragma unroll
  for (int j = 0; j < NPT; ++j) { raw[j] = cnt[lo + j]; sum += raw[j]; }
  int incl = sum;
#pragma unroll
  for (int off = 1; off < 64; off <<= 1) {
    int v = __shfl_up(incl, off);
    if ((threadIdx.x & 63) >= off) incl += v;
  }
  if ((threadIdx.x & 63) == 63) wsum[t >> 6] = incl;
  __syncthreads();
  int wb = 0;
  for (int w = 0; w < (t >> 6); ++w) wb += wsum[w];
  int run = wb + incl - sum;  // block-wide exclusive prefix for this thread's range
#pragma unroll
  for (int j = 0; j < NPT; ++j) {
    cnt[lo + j] = run;  // cursor for Pass C
    combo[(size_t)(lo + j) * NB + b] = ((unsigned)raw[j] << 16) | (unsigned)run;
    run += raw[j];
  }
  __syncthreads();

  // Pass C: rank (LDS atomic rtn) + scatter into LDS sorted list
  for (int i = t; i < EPB / 4; i += 256) {
    int4 s4 = src4[i];
    int4 d4 = dst4[i];
    int ss[4] = {s4.x, s4.y, s4.z, s4.w};
    int dd[4] = {d4.x, d4.y, d4.z, d4.w};
#pragma unroll
    for (int u = 0; u < 4; ++u) {
      int pos = atomicAdd(&cnt[dd[u]], 1);
      sorted[pos] = (unsigned short)ss[u];
    }
  }
  __syncthreads();

  // stream out coalesced (5000 ushort = 2500 uint)
  unsigned int* outb = (unsigned int*)(bins + (size_t)b * EPB);
  const unsigned int* s32 = (const unsigned int*)sorted;
  for (int i = t; i < EPB / 2; i += 256) outb[i] = s32[i];
}

// ---------------------------------------------------------------------------
// k_agg: one wave per node (2500 blocks x 4 waves, N=10000 exact -> no tail).
// Lane l owns block-segments {2l, 2l+1}: one dwordx2 combo load per lane.
// Shuffle prefix -> parallel fill of per-wave LDS src list (64 concurrent
// 2-B gathers) -> 8-deep pipelined 1-KB row gathers -> shfl_xor reduce ->
// fused /deg + z[n] + bias + relu -> fp32 out.
// ---------------------------------------------------------------------------
__global__ void k_agg(const unsigned int* __restrict__ combo,
                      const unsigned short* __restrict__ bins,
                      const __hip_bfloat16* __restrict__ zb,
                      const float* __restrict__ bias,
                      float* __restrict__ out, int N) {
  __shared__ unsigned short list[4][LCAP];

  const int wid = threadIdx.x >> 6;
  const int lane = threadIdx.x & 63;
  const int n = blockIdx.x * 4 + wid;

  // segment metadata: blocks 2*lane and 2*lane+1
  uint2 c01 = ((const uint2*)(combo + (size_t)n * NB))[lane];
  int cnt0 = c01.x >> 16, off0 = c01.x & 0xFFFF;
  int cnt1 = c01.y >> 16, off1 = c01.y & 0xFFFF;
  int cl = cnt0 + cnt1;

  // exclusive prefix + total via shuffles
  int incl = cl;
#pragma unroll
  for (int off = 1; off < 64; off <<= 1) {
    int v = __shfl_up(incl, off);
    if (lane >= off) incl += v;
  }
  int p = incl - cl;
  int m = __shfl(incl, 63);  // true degree of node n

  // fill per-wave src list (lane-parallel 2-B gathers)
  const unsigned short* b0 = bins + (size_t)(2 * lane) * EPB + off0;
  const unsigned short* b1 = bins + (size_t)(2 * lane + 1) * EPB + off1;
  for (int j = 0; j < cnt0; ++j)
    if (p + j < LCAP) list[wid][p + j] = b0[j];
  for (int j = 0; j < cnt1; ++j)
    if (p + cnt0 + j < LCAP) list[wid][p + cnt0 + j] = b1[j];
  __syncthreads();  // all 4 waves pass exactly once

  const int g = lane >> 4;    // row-group
  const int sub = lane & 15;  // 16B chunk of 256B row
  int mm = m < LCAP ? m : LCAP;

  float acc[8] = {0.f, 0.f, 0.f, 0.f, 0.f, 0.f, 0.f, 0.f};
  for (int e = 0; e < mm; e += 32) {
#pragma unroll
    for (int u = 0; u < 8; ++u) {
      int idx = e + u * 4 + g;
      if (idx < mm) {
        int s = list[wid][idx];
        bf16_8 v = *(const bf16_8*)(zb + (size_t)s * 128 + sub * 8);
#pragma unroll
        for (int k = 0; k < 8; ++k) acc[k] += (float)v[k];
      }
    }
  }
#pragma unroll
  for (int k = 0; k < 8; ++k) {
    acc[k] += __shfl_xor(acc[k], 16);
    acc[k] += __shfl_xor(acc[k], 32);
  }

  if (g == 0 && n < N) {
    float inv = 1.f / (float)(m > 0 ? m : 1);
    bf16_8 zn = *(const bf16_8*)(zb + (size_t)n * 128 + sub * 8);
    f32_8 bv = *(const f32_8*)(bias + sub * 8);
    float r[8];
#pragma unroll
    for (int k = 0; k < 8; ++k) {
      float v = acc[k] * inv + (float)zn[k] + bv[k];
      r[k] = v > 0.f ? v : 0.f;
    }
    float* o = out + (size_t)n * 128 + sub * 8;
    *(float4*)(o)     = make_float4(r[0], r[1], r[2], r[3]);
    *(float4*)(o + 4) = make_float4(r[4], r[5], r[6], r[7]);
  }
}

// ---------------------------------------------------------------------------
extern "C" void kernel_launch(void* const* d_in, const int* in_sizes, int n_in,
                              void* d_out, int out_size, void* d_ws, size_t ws_size,
                              hipStream_t stream) {
  const float* x = (const float*)d_in[0];
  const int* ei = (const int*)d_in[1];
  const float* W = (const float*)d_in[2];
  const float* b = (const float*)d_in[3];
  float* out = (float*)d_out;

  const int N = in_sizes[0] / 128;  // 10000
  const int E = in_sizes[1] / 2;    // 640000 (= NB * EPB)

  char* ws = (char*)d_ws;
  size_t off = 0;
  auto carve = [&](size_t bytes) {
    void* p = ws + off;
    off = (off + bytes + 255) & ~(size_t)255;
    return p;
  };
  __hip_bfloat16* zb = (__hip_bfloat16*)carve((size_t)N * 128 * 2);        // 2.56 MB
  unsigned short* bins = (unsigned short*)carve((size_t)NB * EPB * 2);     // 1.28 MB
  unsigned int* combo = (unsigned int*)carve((size_t)NPAD * NB * 4);       // 5.24 MB

  // 1) z = x @ W^T (bf16)
  k_zgemm<<<N / 16, 256, 0, stream>>>(x, W, zb);
  // 2) per-block counting sort of edges by destination (no global atomics)
  k_sortbin<<<NB, 256, 0, stream>>>(ei, E, bins, combo);
  // 3) gather + segment-sum + /deg + z[n] + bias + relu
  k_agg<<<N / 4, 256, 0, stream>>>(combo, bins, zb, b, out, N);
}

// Round 6
// 110.411 us; speedup vs baseline: 1.2559x; 1.0065x over previous
//
#include <hip/hip_runtime.h>
#include <hip/hip_bf16.h>

// Problem constants (fixed by reference): N=10000, D=128, E=640000.
#define NB    256      // sort blocks; each owns E/NB edges
#define EPB   2500     // edges per sort block
#define NPAD  10240    // scan width: 256 threads * 40 nodes
#define NPT   40       // nodes per thread in scan
#define NGEMM 625      // gemm role blocks (10000/16)
#define LCAP  1024     // per-wave src-list capacity (max degree ~110 for this input)

typedef __bf16 bf16_8 __attribute__((ext_vector_type(8)));
typedef float f32_4 __attribute__((ext_vector_type(4)));
typedef float f32_8 __attribute__((ext_vector_type(8)));

// ---------------------------------------------------------------------------
// k_fused: blockIdx-split roles.
//  blocks [0,625):      z = x @ W^T  (bf16 MFMA 16x16x32, inline f32->bf16)
//  blocks [625,625+256): counting-sort 2500 edges by dst (LDS only, no global
//                        atomics). Histogram & cursors are ushort-pairs packed
//                        in int (counts <= 2500 => no cross-field carry).
// Outputs: bins[b][0..2499] (src ushort grouped by dst, coalesced store),
//          combo[b][n] = (count<<16)|excl_off  (coalesced uint4 stores).
// ---------------------------------------------------------------------------
__global__ void __launch_bounds__(256) k_fused(
    const float* __restrict__ x, const float* __restrict__ W,
    const int* __restrict__ ei, int E,
    __hip_bfloat16* __restrict__ zb, unsigned short* __restrict__ bins,
    unsigned int* __restrict__ combo) {
  __shared__ int h[NPAD / 2];               // 20.5 KB packed counts -> cursors
  __shared__ unsigned short sorted[EPB];    // 5 KB
  __shared__ int wsum[4];

  if (blockIdx.x < NGEMM) {
    // ---- zgemm role: einsum('nd,od->no') => B[k][n] = W[n][k], read W rows.
    // A frag: A[m=lane&15][k=quad*8+j]; C/D: col=lane&15, row=quad*4+reg (m89).
    int rowbase = blockIdx.x * 16;
    int wid = threadIdx.x >> 6;
    int lane = threadIdx.x & 63;
    int m16 = lane & 15;
    int quad = lane >> 4;

    union { bf16_8 v; __hip_bfloat16 h8[8]; } ac[4];
    const float* arow = x + (size_t)(rowbase + m16) * 128 + quad * 8;
#pragma unroll
    for (int kk = 0; kk < 4; ++kk) {
      f32_8 af = *(const f32_8*)(arow + kk * 32);
#pragma unroll
      for (int j = 0; j < 8; ++j) ac[kk].h8[j] = __float2bfloat16(af[j]);
    }
#pragma unroll
    for (int ct = 0; ct < 2; ++ct) {
      int colbase = wid * 32 + ct * 16;
      const float* brow = W + (size_t)(colbase + m16) * 128 + quad * 8;
      f32_4 c = {0.f, 0.f, 0.f, 0.f};
#pragma unroll
      for (int kk = 0; kk < 4; ++kk) {
        f32_8 bf = *(const f32_8*)(brow + kk * 32);
        union { bf16_8 v; __hip_bfloat16 h8[8]; } bc;
#pragma unroll
        for (int j = 0; j < 8; ++j) bc.h8[j] = __float2bfloat16(bf[j]);
        c = __builtin_amdgcn_mfma_f32_16x16x32_bf16(ac[kk].v, bc.v, c, 0, 0, 0);
      }
#pragma unroll
      for (int r = 0; r < 4; ++r) {
        int row = rowbase + quad * 4 + r;
        zb[(size_t)row * 128 + colbase + m16] = __float2bfloat16(c[r]);
      }
    }
    return;
  }

  // ---- sort role ----
  const int b = blockIdx.x - NGEMM;
  const int t = threadIdx.x;
  const int4* src4 = (const int4*)(ei) + b * (EPB / 4);
  const int4* dst4 = (const int4*)(ei + E) + b * (EPB / 4);

  for (int i = t; i < NPAD / 2; i += 256) h[i] = 0;
  __syncthreads();

  // Pass A: histogram (packed-pair LDS atomics)
  for (int i = t; i < EPB / 4; i += 256) {
    int4 d = dst4[i];
    atomicAdd(&h[d.x >> 1], 1 << ((d.x & 1) * 16));
    atomicAdd(&h[d.y >> 1], 1 << ((d.y & 1) * 16));
    atomicAdd(&h[d.z >> 1], 1 << ((d.z & 1) * 16));
    atomicAdd(&h[d.w >> 1], 1 << ((d.w & 1) * 16));
  }
  __syncthreads();

  // Pass B: block-wide exclusive scan; emit packed cursors + combo row.
  int raw[NPT];
  const int lo = t * NPT;  // even
  int sum = 0;
#pragma unroll
  for (int j = 0; j < NPT; j += 2) {
    int pair = h[(lo + j) >> 1];
    raw[j] = pair & 0xFFFF;
    raw[j + 1] = (pair >> 16) & 0xFFFF;
    sum += raw[j] + raw[j + 1];
  }
  int incl = sum;
#pragma unroll
  for (int off = 1; off < 64; off <<= 1) {
    int v = __shfl_up(incl, off);
    if ((t & 63) >= off) incl += v;
  }
  if ((t & 63) == 63) wsum[t >> 6] = incl;
  __syncthreads();
  int wb = 0;
  for (int w = 0; w < (t >> 6); ++w) wb += wsum[w];
  int run = wb + incl - sum;  // block-wide exclusive prefix for this range

  unsigned int cpack[NPT];
#pragma unroll
  for (int j = 0; j < NPT; j += 2) {
    int r0 = run; run += raw[j];
    int r1 = run; run += raw[j + 1];
    h[(lo + j) >> 1] = (r1 << 16) | r0;  // packed cursors for Pass C
    cpack[j]     = ((unsigned)raw[j] << 16) | (unsigned)r0;
    cpack[j + 1] = ((unsigned)raw[j + 1] << 16) | (unsigned)r1;
  }
  __syncthreads();

  // combo row write: fully coalesced (10 x uint4 per thread)
  unsigned int* crow = combo + (size_t)b * NPAD + lo;
#pragma unroll
  for (int j = 0; j < NPT; j += 4)
    *(uint4*)(crow + j) = make_uint4(cpack[j], cpack[j+1], cpack[j+2], cpack[j+3]);

  // Pass C: rank via packed-pair atomic rtn, scatter into LDS sorted list
  for (int i = t; i < EPB / 4; i += 256) {
    int4 s4 = src4[i];
    int4 d4 = dst4[i];
    int ss[4] = {s4.x, s4.y, s4.z, s4.w};
    int dd[4] = {d4.x, d4.y, d4.z, d4.w};
#pragma unroll
    for (int u = 0; u < 4; ++u) {
      int n = dd[u];
      int sh = (n & 1) * 16;
      int pos = (atomicAdd(&h[n >> 1], 1 << sh) >> sh) & 0xFFFF;
      sorted[pos] = (unsigned short)ss[u];
    }
  }
  __syncthreads();

  // stream out coalesced (2500 ushort = 1250 uint)
  unsigned int* outb = (unsigned int*)(bins + (size_t)b * EPB);
  const unsigned int* s32 = (const unsigned int*)sorted;
  for (int i = t; i < EPB / 2; i += 256) outb[i] = s32[i];
}

// ---------------------------------------------------------------------------
// k_agg: block = 4 nodes (one per wave). Per-block combo un-transpose:
// thread t does ONE aligned 16-B read combo[t][n0..n0+3] -> LDS transpose.
// Lane l then owns segments {4l..4l+3}; shuffle prefix -> parallel LDS src
// list fill -> 8-deep pipelined 1-KB row gathers -> shfl_xor reduce ->
// fused /deg + z[n] + bias + relu -> fp32 out.
// ---------------------------------------------------------------------------
__global__ void __launch_bounds__(256) k_agg(
    const unsigned int* __restrict__ combo, const unsigned short* __restrict__ bins,
    const __hip_bfloat16* __restrict__ zb, const float* __restrict__ bias,
    float* __restrict__ out, int N) {
  __shared__ unsigned int trans[4][256];      // 4 KB
  __shared__ unsigned short list[4][LCAP];    // 8 KB

  const int t = threadIdx.x;
  const int wid = t >> 6;
  const int lane = t & 63;
  const int n0 = blockIdx.x * 4;

  uint4 cm = *(const uint4*)(combo + (size_t)t * NPAD + n0);
  trans[0][t] = cm.x; trans[1][t] = cm.y; trans[2][t] = cm.z; trans[3][t] = cm.w;
  __syncthreads();

  const int n = n0 + wid;
  uint4 cc = *(const uint4*)&trans[wid][4 * lane];
  int c0 = cc.x >> 16, o0 = cc.x & 0xFFFF;
  int c1 = cc.y >> 16, o1 = cc.y & 0xFFFF;
  int c2 = cc.z >> 16, o2 = cc.z & 0xFFFF;
  int c3 = cc.w >> 16, o3 = cc.w & 0xFFFF;
  int cl = c0 + c1 + c2 + c3;

  int incl = cl;
#pragma unroll
  for (int off = 1; off < 64; off <<= 1) {
    int v = __shfl_up(incl, off);
    if (lane >= off) incl += v;
  }
  int p = incl - cl;          // exclusive prefix
  int m = __shfl(incl, 63);   // true degree of node n

  // fill per-wave src list (lane-parallel 2-B gathers; avg ~1 edge/lane)
  {
    int q = p;
    int cs[4] = {c0, c1, c2, c3};
    int os[4] = {o0, o1, o2, o3};
#pragma unroll
    for (int k = 0; k < 4; ++k) {
      const unsigned short* bk = bins + (size_t)(4 * lane + k) * EPB + os[k];
      for (int j = 0; j < cs[k]; ++j) {
        if (q < LCAP) list[wid][q] = bk[j];
        ++q;
      }
    }
  }
  __syncthreads();

  const int g = lane >> 4;    // row-group
  const int sub = lane & 15;  // 16-B chunk of 256-B row
  int mm = m < LCAP ? m : LCAP;

  float acc[8] = {0.f, 0.f, 0.f, 0.f, 0.f, 0.f, 0.f, 0.f};
  for (int e = 0; e < mm; e += 32) {
#pragma unroll
    for (int u = 0; u < 8; ++u) {
      int idx = e + u * 4 + g;
      if (idx < mm) {
        int s = list[wid][idx];
        bf16_8 v = *(const bf16_8*)(zb + (size_t)s * 128 + sub * 8);
#pragma unroll
        for (int k = 0; k < 8; ++k) acc[k] += (float)v[k];
      }
    }
  }
#pragma unroll
  for (int k = 0; k < 8; ++k) {
    acc[k] += __shfl_xor(acc[k], 16);
    acc[k] += __shfl_xor(acc[k], 32);
  }

  if (g == 0 && n < N) {
    float inv = 1.f / (float)(m > 0 ? m : 1);
    bf16_8 zn = *(const bf16_8*)(zb + (size_t)n * 128 + sub * 8);
    f32_8 bv = *(const f32_8*)(bias + sub * 8);
    float r[8];
#pragma unroll
    for (int k = 0; k < 8; ++k) {
      float v = acc[k] * inv + (float)zn[k] + bv[k];
      r[k] = v > 0.f ? v : 0.f;
    }
    float* o = out + (size_t)n * 128 + sub * 8;
    *(float4*)(o)     = make_float4(r[0], r[1], r[2], r[3]);
    *(float4*)(o + 4) = make_float4(r[4], r[5], r[6], r[7]);
  }
}

// ---------------------------------------------------------------------------
extern "C" void kernel_launch(void* const* d_in, const int* in_sizes, int n_in,
                              void* d_out, int out_size, void* d_ws, size_t ws_size,
                              hipStream_t stream) {
  const float* x = (const float*)d_in[0];
  const int* ei = (const int*)d_in[1];
  const float* W = (const float*)d_in[2];
  const float* b = (const float*)d_in[3];
  float* out = (float*)d_out;

  const int N = in_sizes[0] / 128;  // 10000
  const int E = in_sizes[1] / 2;    // 640000 (= NB * EPB)

  char* ws = (char*)d_ws;
  size_t off = 0;
  auto carve = [&](size_t bytes) {
    void* p = ws + off;
    off = (off + bytes + 255) & ~(size_t)255;
    return p;
  };
  __hip_bfloat16* zb = (__hip_bfloat16*)carve((size_t)N * 128 * 2);     // 2.56 MB
  unsigned short* bins = (unsigned short*)carve((size_t)NB * EPB * 2);  // 1.28 MB
  unsigned int* combo = (unsigned int*)carve((size_t)NB * NPAD * 4);    // 10.5 MB

  // 1) fused: z = x@W^T (blocks 0..624) || per-block counting sort (625..880)
  k_fused<<<NGEMM + NB, 256, 0, stream>>>(x, W, ei, E, zb, bins, combo);
  // 2) gather + segment-sum + /deg + z[n] + bias + relu
  k_agg<<<N / 4, 256, 0, stream>>>(combo, bins, zb, b, out, N);
}

// Round 7
// 108.592 us; speedup vs baseline: 1.2769x; 1.0167x over previous
//
#include <hip/hip_runtime.h>
#include <hip/hip_bf16.h>

// Problem constants (fixed by reference): N=10000, D=128, E=640000.
#define NB    256      // sort blocks; each owns E/NB edges
#define EPB   2500     // edges per sort block
#define NPAD  10240    // scan width: 256 threads * 40 nodes
#define NPT   40       // nodes per thread in scan
#define NGEMM 625      // gemm role blocks (10000/16)
#define LCAP  1024     // per-wave src-list capacity (max degree ~110 for this input)

typedef __bf16 bf16_8 __attribute__((ext_vector_type(8)));
typedef float f32_4 __attribute__((ext_vector_type(4)));
typedef float f32_8 __attribute__((ext_vector_type(8)));

// ---------------------------------------------------------------------------
// k_fused: blockIdx-split roles (unchanged from R6).
//  blocks [0,625):      z = x @ W^T  (bf16 MFMA 16x16x32, inline f32->bf16)
//  blocks [625,625+256): counting-sort 2500 edges by dst (LDS only).
// Outputs: bins[b][0..2499] (src ushort grouped by dst, coalesced store),
//          combo[b][n] = (count<<16)|excl_off  (coalesced uint4 stores).
// ---------------------------------------------------------------------------
__global__ void __launch_bounds__(256) k_fused(
    const float* __restrict__ x, const float* __restrict__ W,
    const int* __restrict__ ei, int E,
    __hip_bfloat16* __restrict__ zb, unsigned short* __restrict__ bins,
    unsigned int* __restrict__ combo) {
  __shared__ int h[NPAD / 2];               // 20.5 KB packed counts -> cursors
  __shared__ unsigned short sorted[EPB];    // 5 KB
  __shared__ int wsum[4];

  if (blockIdx.x < NGEMM) {
    // ---- zgemm role: einsum('nd,od->no') => B[k][n] = W[n][k], read W rows.
    // A frag: A[m=lane&15][k=quad*8+j]; C/D: col=lane&15, row=quad*4+reg (m89).
    int rowbase = blockIdx.x * 16;
    int wid = threadIdx.x >> 6;
    int lane = threadIdx.x & 63;
    int m16 = lane & 15;
    int quad = lane >> 4;

    union { bf16_8 v; __hip_bfloat16 h8[8]; } ac[4];
    const float* arow = x + (size_t)(rowbase + m16) * 128 + quad * 8;
#pragma unroll
    for (int kk = 0; kk < 4; ++kk) {
      f32_8 af = *(const f32_8*)(arow + kk * 32);
#pragma unroll
      for (int j = 0; j < 8; ++j) ac[kk].h8[j] = __float2bfloat16(af[j]);
    }
#pragma unroll
    for (int ct = 0; ct < 2; ++ct) {
      int colbase = wid * 32 + ct * 16;
      const float* brow = W + (size_t)(colbase + m16) * 128 + quad * 8;
      f32_4 c = {0.f, 0.f, 0.f, 0.f};
#pragma unroll
      for (int kk = 0; kk < 4; ++kk) {
        f32_8 bf = *(const f32_8*)(brow + kk * 32);
        union { bf16_8 v; __hip_bfloat16 h8[8]; } bc;
#pragma unroll
        for (int j = 0; j < 8; ++j) bc.h8[j] = __float2bfloat16(bf[j]);
        c = __builtin_amdgcn_mfma_f32_16x16x32_bf16(ac[kk].v, bc.v, c, 0, 0, 0);
      }
#pragma unroll
      for (int r = 0; r < 4; ++r) {
        int row = rowbase + quad * 4 + r;
        zb[(size_t)row * 128 + colbase + m16] = __float2bfloat16(c[r]);
      }
    }
    return;
  }

  // ---- sort role ----
  const int b = blockIdx.x - NGEMM;
  const int t = threadIdx.x;
  const int4* src4 = (const int4*)(ei) + b * (EPB / 4);
  const int4* dst4 = (const int4*)(ei + E) + b * (EPB / 4);

  for (int i = t; i < NPAD / 2; i += 256) h[i] = 0;
  __syncthreads();

  // Pass A: histogram (packed-pair LDS atomics)
  for (int i = t; i < EPB / 4; i += 256) {
    int4 d = dst4[i];
    atomicAdd(&h[d.x >> 1], 1 << ((d.x & 1) * 16));
    atomicAdd(&h[d.y >> 1], 1 << ((d.y & 1) * 16));
    atomicAdd(&h[d.z >> 1], 1 << ((d.z & 1) * 16));
    atomicAdd(&h[d.w >> 1], 1 << ((d.w & 1) * 16));
  }
  __syncthreads();

  // Pass B: block-wide exclusive scan; emit packed cursors + combo row.
  int raw[NPT];
  const int lo = t * NPT;  // even
  int sum = 0;
#pragma unroll
  for (int j = 0; j < NPT; j += 2) {
    int pair = h[(lo + j) >> 1];
    raw[j] = pair & 0xFFFF;
    raw[j + 1] = (pair >> 16) & 0xFFFF;
    sum += raw[j] + raw[j + 1];
  }
  int incl = sum;
#pragma unroll
  for (int off = 1; off < 64; off <<= 1) {
    int v = __shfl_up(incl, off);
    if ((t & 63) >= off) incl += v;
  }
  if ((t & 63) == 63) wsum[t >> 6] = incl;
  __syncthreads();
  int wb = 0;
  for (int w = 0; w < (t >> 6); ++w) wb += wsum[w];
  int run = wb + incl - sum;  // block-wide exclusive prefix for this range

  unsigned int cpack[NPT];
#pragma unroll
  for (int j = 0; j < NPT; j += 2) {
    int r0 = run; run += raw[j];
    int r1 = run; run += raw[j + 1];
    h[(lo + j) >> 1] = (r1 << 16) | r0;  // packed cursors for Pass C
    cpack[j]     = ((unsigned)raw[j] << 16) | (unsigned)r0;
    cpack[j + 1] = ((unsigned)raw[j + 1] << 16) | (unsigned)r1;
  }
  __syncthreads();

  // combo row write: fully coalesced (10 x uint4 per thread)
  unsigned int* crow = combo + (size_t)b * NPAD + lo;
#pragma unroll
  for (int j = 0; j < NPT; j += 4)
    *(uint4*)(crow + j) = make_uint4(cpack[j], cpack[j+1], cpack[j+2], cpack[j+3]);

  // Pass C: rank via packed-pair atomic rtn, scatter into LDS sorted list
  for (int i = t; i < EPB / 4; i += 256) {
    int4 s4 = src4[i];
    int4 d4 = dst4[i];
    int ss[4] = {s4.x, s4.y, s4.z, s4.w};
    int dd[4] = {d4.x, d4.y, d4.z, d4.w};
#pragma unroll
    for (int u = 0; u < 4; ++u) {
      int n = dd[u];
      int sh = (n & 1) * 16;
      int pos = (atomicAdd(&h[n >> 1], 1 << sh) >> sh) & 0xFFFF;
      sorted[pos] = (unsigned short)ss[u];
    }
  }
  __syncthreads();

  // stream out coalesced (2500 ushort = 1250 uint)
  unsigned int* outb = (unsigned int*)(bins + (size_t)b * EPB);
  const unsigned int* s32 = (const unsigned int*)sorted;
  for (int i = t; i < EPB / 2; i += 256) outb[i] = s32[i];
}

// ---------------------------------------------------------------------------
// k_agg (restructured): block = 4 nodes (one per wave).
//  1. combo un-transpose via LDS (one aligned uint4 per thread).
//  2. LDS-cursor compaction: one LDS atomicAdd per lane reserves slots
//     (no shuffle prefix chain); degree = cursor readback.
//  3. Fill: 3 guarded INDEPENDENT 2-B loads per segment x 4 segments,
//     all issued before one waitcnt (was: serial loop w/ vmcnt(0) each).
//     P(seg count > 3 | lambda=0.25) ~ 1e-4 -> rare scalar tail.
//  4. 8-deep pipelined 1-KB row gathers -> shfl_xor reduce -> epilogue.
// ---------------------------------------------------------------------------
__global__ void __launch_bounds__(256) k_agg(
    const unsigned int* __restrict__ combo, const unsigned short* __restrict__ bins,
    const __hip_bfloat16* __restrict__ zb, const float* __restrict__ bias,
    float* __restrict__ out, int N) {
  __shared__ unsigned int trans[4][256];      // 4 KB
  __shared__ unsigned short list[4][LCAP];    // 8 KB
  __shared__ int cursor[4];

  const int t = threadIdx.x;
  const int wid = t >> 6;
  const int lane = t & 63;
  const int n0 = blockIdx.x * 4;

  if (t < 4) cursor[t] = 0;
  uint4 cm = *(const uint4*)(combo + (size_t)t * NPAD + n0);
  trans[0][t] = cm.x; trans[1][t] = cm.y; trans[2][t] = cm.z; trans[3][t] = cm.w;
  __syncthreads();

  const int n = n0 + wid;
  uint4 cc = *(const uint4*)&trans[wid][4 * lane];
  int cs[4] = {(int)(cc.x >> 16), (int)(cc.y >> 16), (int)(cc.z >> 16), (int)(cc.w >> 16)};
  int os[4] = {(int)(cc.x & 0xFFFF), (int)(cc.y & 0xFFFF), (int)(cc.z & 0xFFFF), (int)(cc.w & 0xFFFF)};
  int tot = cs[0] + cs[1] + cs[2] + cs[3];

  int p = atomicAdd(&cursor[wid], tot);  // LDS cursor: order-free slot reserve

  {
    int q = p;
#pragma unroll
    for (int k = 0; k < 4; ++k) {
      int c = cs[k];
      const unsigned short* bk = bins + (size_t)(4 * lane + k) * EPB + os[k];
      unsigned short s0 = 0, s1 = 0, s2 = 0;
      if (c > 0) s0 = bk[0];           // independent guarded loads:
      if (c > 1) s1 = bk[1];           // compiler issues all, waits once
      if (c > 2) s2 = bk[2];
      if (c > 0 && q < LCAP) list[wid][q] = s0;
      if (c > 1 && q + 1 < LCAP) list[wid][q + 1] = s1;
      if (c > 2 && q + 2 < LCAP) list[wid][q + 2] = s2;
      for (int j = 3; j < c; ++j)      // rare tail (P ~ 1e-4 per segment)
        if (q + j < LCAP) list[wid][q + j] = bk[j];
      q += c;
    }
  }
  __syncthreads();

  const int m = cursor[wid];  // true degree of node n
  const int g = lane >> 4;    // row-group
  const int sub = lane & 15;  // 16-B chunk of 256-B row
  int mm = m < LCAP ? m : LCAP;

  float acc[8] = {0.f, 0.f, 0.f, 0.f, 0.f, 0.f, 0.f, 0.f};
  for (int e = 0; e < mm; e += 32) {
#pragma unroll
    for (int u = 0; u < 8; ++u) {
      int idx = e + u * 4 + g;
      if (idx < mm) {
        int s = list[wid][idx];
        bf16_8 v = *(const bf16_8*)(zb + (size_t)s * 128 + sub * 8);
#pragma unroll
        for (int k = 0; k < 8; ++k) acc[k] += (float)v[k];
      }
    }
  }
#pragma unroll
  for (int k = 0; k < 8; ++k) {
    acc[k] += __shfl_xor(acc[k], 16);
    acc[k] += __shfl_xor(acc[k], 32);
  }

  if (g == 0 && n < N) {
    float inv = 1.f / (float)(m > 0 ? m : 1);
    bf16_8 zn = *(const bf16_8*)(zb + (size_t)n * 128 + sub * 8);
    f32_8 bv = *(const f32_8*)(bias + sub * 8);
    float r[8];
#pragma unroll
    for (int k = 0; k < 8; ++k) {
      float v = acc[k] * inv + (float)zn[k] + bv[k];
      r[k] = v > 0.f ? v : 0.f;
    }
    float* o = out + (size_t)n * 128 + sub * 8;
    *(float4*)(o)     = make_float4(r[0], r[1], r[2], r[3]);
    *(float4*)(o + 4) = make_float4(r[4], r[5], r[6], r[7]);
  }
}

// ---------------------------------------------------------------------------
extern "C" void kernel_launch(void* const* d_in, const int* in_sizes, int n_in,
                              void* d_out, int out_size, void* d_ws, size_t ws_size,
                              hipStream_t stream) {
  const float* x = (const float*)d_in[0];
  const int* ei = (const int*)d_in[1];
  const float* W = (const float*)d_in[2];
  const float* b = (const float*)d_in[3];
  float* out = (float*)d_out;

  const int N = in_sizes[0] / 128;  // 10000
  const int E = in_sizes[1] / 2;    // 640000 (= NB * EPB)

  char* ws = (char*)d_ws;
  size_t off = 0;
  auto carve = [&](size_t bytes) {
    void* p = ws + off;
    off = (off + bytes + 255) & ~(size_t)255;
    return p;
  };
  __hip_bfloat16* zb = (__hip_bfloat16*)carve((size_t)N * 128 * 2);     // 2.56 MB
  unsigned short* bins = (unsigned short*)carve((size_t)NB * EPB * 2);  // 1.28 MB
  unsigned int* combo = (unsigned int*)carve((size_t)NB * NPAD * 4);    // 10.5 MB

  // 1) fused: z = x@W^T (blocks 0..624) || per-block counting sort (625..880)
  k_fused<<<NGEMM + NB, 256, 0, stream>>>(x, W, ei, E, zb, bins, combo);
  // 2) gather + segment-sum + /deg + z[n] + bias + relu
  k_agg<<<N / 4, 256, 0, stream>>>(combo, bins, zb, b, out, N);
}